// Round 9
// baseline (116.849 us; speedup 1.0000x reference)
//
#include <hip/hip_runtime.h>

// HistByProfMultiChannel: x (16,128,56,56) f32, hist_edges (128,10) f32,
// out (16,128,11) f32.
//
// R9: biased geometric chain (fixes R8's FTZ poisoning) + packed VALU + probe.
//  - All Gaussian terms computed as g~ = 2^88 * g (bias folded into the
//    exp2 anchor constants). Chain g~_{j+1} = g~_j * r, r *= rho, anchors at
//    bins 1 and 6 (spans <= 4). Anchor FTZ now only when the farthest
//    chained bin's true value <= 1.2e-6 (R8 failed at 0.3). acc[0..9] are
//    rescaled by 2^-88 after the block reduction (exact).
//  - 5 exp2 + 1 rcp per pixel (R2 had 12 trans, R7 had 7).
//  - float2 ext-vector math -> v_pk_fma_f32/v_pk_mul_f32.
//  - Probe <R=14> repeats compute (asm value-barrier; loads not repeated)
//    -> d_ws, surfaces in rocprof top-5 with counters for THIS body.

#define NE 10
#define NBINS 11
#define HW 3136
#define HW4 784
#define NCH 128
#define BIAS 88.0f

typedef float v2f __attribute__((ext_vector_type(2)));

__device__ __forceinline__ float rfl(float xv) {
    return __int_as_float(__builtin_amdgcn_readfirstlane(__float_as_int(xv)));
}
__device__ __forceinline__ v2f exp2v(v2f a) {
    v2f r;
    r.x = __builtin_amdgcn_exp2f(a.x);
    r.y = __builtin_amdgcn_exp2f(a.y);
    return r;
}

template<int R>
__global__ __launch_bounds__(256)
void hist_kernel(const float* __restrict__ x,
                 const float* __restrict__ edges,
                 float* __restrict__ out) {
    const int bc  = blockIdx.x;          // bt*NCH + c
    const int c   = bc & (NCH - 1);
    const int tid = threadIdx.x;

    const float LOG2E = 1.4426950408889634f;

    float e[NE];
    #pragma unroll
    for (int j = 0; j < NE; ++j) e[j] = rfl(edges[c * NE + j]);

    // ---- 16 pixels per thread ----
    const float4* xp = (const float4*)(x + (size_t)bc * HW);
    float4 p0 = xp[tid];
    float4 p1 = xp[tid + 256];
    float4 p2 = xp[tid + 512];
    float4 p3;
    if (tid < (HW4 - 768)) p3 = xp[768 + tid];
    else { p3.x = p3.y = p3.z = p3.w = -1e18f; }   // sentinel -> all profiles 0

    v2f pr[8] = {{p0.x,p0.y},{p0.z,p0.w},{p1.x,p1.y},{p1.z,p1.w},
                 {p2.x,p2.y},{p2.z,p2.w},{p3.x,p3.y},{p3.z,p3.w}};

    v2f acc2[NBINS];
    #pragma unroll
    for (int j = 0; j < NBINS; ++j) acc2[j] = (v2f){0.f, 0.f};

    // Uniform-spacing check (wave-uniform).
    const float D = e[1] - e[0];
    bool uniform = (D > 1e-6f);
    #pragma unroll
    for (int j = 1; j < NE - 1; ++j)
        uniform = uniform && (fabsf((e[j + 1] - e[j]) - D) <= 1e-4f * fabsf(D));

    const float sB = rfl(-20.0f * LOG2E);
    const float sC = rfl(20.0f * LOG2E * e[NE - 1]);

    if (uniform) {
        const float sg   = -D * (1.0f / 3.0f) + 1e-6f;
        const float A    = rfl(-0.5f * LOG2E / (sg * sg));   // < 0 (log2 space)
        const float mu1  = e[0] + 0.5f * D;
        const float mu6  = e[0] + 5.5f * D;
        // Biased constants: t~ = A*v^2 + B*v + (C + BIAS)
        const float B0 = rfl(-2.0f * A * e[0]), C0 = rfl(A * e[0] * e[0] + BIAS);
        const float B1 = rfl(-2.0f * A * mu1),  C1 = rfl(A * mu1 * mu1 + BIAS);
        const float B6 = rfl(-2.0f * A * mu6),  C6 = rfl(A * mu6 * mu6 + BIAS);
        const float dB  = rfl(-2.0f * A * D);                 // > 0 (unbiased)
        const float dC  = rfl(A * D * (mu1 + mu1 + D));       // r1 = g2/g1
        const float rho  = rfl(__builtin_amdgcn_exp2f(2.0f * A * D * D)); // < 1
        const float rho2 = rfl(rho * rho);
        const float HC  = rfl((126.0f - dC) / dB);   // keep r finite

        #pragma unroll 1
        for (int r_it = 0; r_it < R; ++r_it) {
            #pragma unroll
            for (int k = 0; k < 8; ++k) {
                float a0 = pr[k].x, a1 = pr[k].y;
                asm volatile("" : "+v"(a0), "+v"(a1));   // defeat LICM across r_it
                v2f v  = (v2f){a0, a1};
                v2f vg = __builtin_elementwise_min(v, (v2f){HC, HC});
                v2f q  = vg * vg;
                v2f t0 = A * q + (B0 * vg + C0);
                v2f t1 = A * q + (B1 * vg + C1);
                v2f t6 = A * q + (B6 * vg + C6);
                v2f rr = exp2v(dB * vg + dC);
                acc2[0] += exp2v(t0);
                v2f g = exp2v(t1);
                acc2[1] += g;
                g *= rr; acc2[2] += g; rr *= rho;
                g *= rr; acc2[3] += g; rr *= rho;
                g *= rr; acc2[4] += g; rr *= rho;
                g *= rr; acc2[5] += g; rr *= rho2;   // rr: r4 -> r6
                v2f h = exp2v(t6);
                acc2[6] += h;
                h *= rr; acc2[7] += h; rr *= rho;
                h *= rr; acc2[8] += h; rr *= rho;
                h *= rr; acc2[9] += h;
                v2f sd = exp2v(sB * v + sC);
                v2f sig;
                sig.x = __builtin_amdgcn_rcpf(1.0f + sd.x);
                sig.y = __builtin_amdgcn_rcpf(1.0f + sd.y);
                acc2[10] += sig;
            }
        }
    } else {
        // General path: direct per-bin quadratic exp2 (unbiased).
        float As[NE], Bs[NE], Cs[NE];
        {
            float mu = e[0];
            float s2 = (e[0] - e[1]) * (1.0f / 3.0f) + 1e-6f;
            float kk = -0.5f * LOG2E / (s2 * s2);
            As[0] = rfl(kk); Bs[0] = rfl(-2.0f * kk * mu); Cs[0] = rfl(kk * mu * mu);
        }
        #pragma unroll
        for (int j = 1; j < NE; ++j) {
            float mu = (e[j - 1] + e[j]) * 0.5f;
            float s2 = (e[j - 1] - e[j]) * (1.0f / 3.0f) + 1e-6f;
            float kk = -0.5f * LOG2E / (s2 * s2);
            As[j] = rfl(kk); Bs[j] = rfl(-2.0f * kk * mu); Cs[j] = rfl(kk * mu * mu);
        }
        #pragma unroll 1
        for (int r_it = 0; r_it < R; ++r_it) {
            #pragma unroll
            for (int k = 0; k < 8; ++k) {
                float a0 = pr[k].x, a1 = pr[k].y;
                asm volatile("" : "+v"(a0), "+v"(a1));
                float vv[2] = {a0, a1};
                #pragma unroll
                for (int h = 0; h < 2; ++h) {
                    float v = vv[h], v2 = v * v;
                    #pragma unroll
                    for (int j = 0; j < NE; ++j) {
                        float arg = fmaf(As[j], v2, fmaf(Bs[j], v, Cs[j]));
                        float g = __builtin_amdgcn_exp2f(arg);
                        if (h == 0) acc2[j].x += g; else acc2[j].y += g;
                    }
                    float den = 1.0f + __builtin_amdgcn_exp2f(fmaf(sB, v, sC));
                    float s = __builtin_amdgcn_rcpf(den);
                    if (h == 0) acc2[10].x += s; else acc2[10].y += s;
                }
            }
        }
    }

    float acc[NBINS];
    #pragma unroll
    for (int j = 0; j < NBINS; ++j) acc[j] = acc2[j].x + acc2[j].y;

    // Wave (64-lane) reduce each accumulator.
    #pragma unroll
    for (int j = 0; j < NBINS; ++j) {
        float a = acc[j];
        #pragma unroll
        for (int off = 32; off > 0; off >>= 1)
            a += __shfl_down(a, off, 64);
        acc[j] = a;
    }

    // Cross-wave reduce via LDS (4 waves x 11 bins).
    __shared__ float red[4][NBINS];
    const int wave = tid >> 6;
    const int lane = tid & 63;
    if (lane == 0) {
        #pragma unroll
        for (int j = 0; j < NBINS; ++j) red[wave][j] = acc[j];
    }
    __syncthreads();
    if (tid < NBINS) {
        float s = red[0][tid] + red[1][tid] + red[2][tid] + red[3][tid];
        // Unbias Gaussian bins (uniform path only); sigmoid bin unbiased.
        const float unb = (uniform && tid < NE) ? 0x1p-88f : 1.0f;
        out[(size_t)bc * NBINS + tid] = s * unb;
    }
}

extern "C" void kernel_launch(void* const* d_in, const int* in_sizes, int n_in,
                              void* d_out, int out_size, void* d_ws, size_t ws_size,
                              hipStream_t stream) {
    const float* x     = (const float*)d_in[0];
    const float* edges = (const float*)d_in[1];
    float* out         = (float*)d_out;
    float* probe_out   = (float*)d_ws;   // scratch; never validated

    hist_kernel<1><<<dim3(16 * NCH), dim3(256), 0, stream>>>(x, edges, out);
    // Diagnostic probe: 14x compute, same body -> surfaces in rocprof top-5.
    hist_kernel<14><<<dim3(16 * NCH), dim3(256), 0, stream>>>(x, edges, probe_out);
}

// Round 10
// 16.161 us; speedup vs baseline: 7.2303x; 7.2303x over previous
//
#include <hip/hip_runtime.h>

// HistByProfMultiChannel: x (16,128,56,56) f32, hist_edges (128,10) f32,
// out (16,128,11) f32.
//
// R10: production kernel (probe removed).
//  - Biased geometric chain (R9): all Gaussian terms carry a 2^88 bias so
//    anchor FTZ only occurs where the chained bin's true value <= 1.2e-6;
//    acc[0..9] unbiased by 2^-88 at the end (exact). 6 trans/px
//    (exp2: t0, t1, t6, r, sigmoid; rcp). Probe R9 measured this body at
//    ~6.8us wall, VALUBusy 86% -- trans ~52% / VALU ~48%, balanced.
//  - Memory/compute overlap: compute for chunk c touches ONLY chunk c's
//    float4 registers, so the compiler can wait vmcnt(3/2/1/0) per chunk
//    instead of draining all loads before the loop (R9 packed pr[8] from
//    all chunks up front -> full serialization: 14.4 = 2 + 4.1mem + 6.8comp).
//  - float2 ext-vector math -> v_pk_fma_f32/v_pk_mul_f32.

#define NE 10
#define NBINS 11
#define HW 3136
#define HW4 784
#define NCH 128
#define BIAS 88.0f

typedef float v2f __attribute__((ext_vector_type(2)));

__device__ __forceinline__ float rfl(float xv) {
    return __int_as_float(__builtin_amdgcn_readfirstlane(__float_as_int(xv)));
}
__device__ __forceinline__ v2f exp2v(v2f a) {
    v2f r;
    r.x = __builtin_amdgcn_exp2f(a.x);
    r.y = __builtin_amdgcn_exp2f(a.y);
    return r;
}

struct UniCoef {
    float A, B0, C0, B1, C1, B6, C6, dB, dC, rho, rho2, HC, sB, sC;
};

// Process two pixels (one v2f) through the biased chain.
__device__ __forceinline__ void chain2(v2f v, const UniCoef& u, v2f* acc2) {
    v2f vg = __builtin_elementwise_min(v, (v2f){u.HC, u.HC});
    v2f q  = vg * vg;
    v2f t0 = u.A * q + (u.B0 * vg + u.C0);
    v2f t1 = u.A * q + (u.B1 * vg + u.C1);
    v2f t6 = u.A * q + (u.B6 * vg + u.C6);
    v2f rr = exp2v(u.dB * vg + u.dC);
    acc2[0] += exp2v(t0);
    v2f g = exp2v(t1);
    acc2[1] += g;
    g *= rr; acc2[2] += g; rr *= u.rho;
    g *= rr; acc2[3] += g; rr *= u.rho;
    g *= rr; acc2[4] += g; rr *= u.rho;
    g *= rr; acc2[5] += g; rr *= u.rho2;   // rr: r4 -> r6
    v2f h = exp2v(t6);
    acc2[6] += h;
    h *= rr; acc2[7] += h; rr *= u.rho;
    h *= rr; acc2[8] += h; rr *= u.rho;
    h *= rr; acc2[9] += h;
    v2f sd = exp2v(u.sB * v + u.sC);
    v2f sig;
    sig.x = __builtin_amdgcn_rcpf(1.0f + sd.x);
    sig.y = __builtin_amdgcn_rcpf(1.0f + sd.y);
    acc2[10] += sig;
}

__global__ __launch_bounds__(256)
void hist_kernel(const float* __restrict__ x,
                 const float* __restrict__ edges,
                 float* __restrict__ out) {
    const int bc  = blockIdx.x;          // bt*NCH + c
    const int c   = bc & (NCH - 1);
    const int tid = threadIdx.x;

    const float LOG2E = 1.4426950408889634f;

    float e[NE];
    #pragma unroll
    for (int j = 0; j < NE; ++j) e[j] = rfl(edges[c * NE + j]);

    // Issue all 4 chunk loads up front; each chunk's compute consumes only
    // its own registers so the compiler waits vmcnt(3/2/1/0) progressively.
    const float4* xp = (const float4*)(x + (size_t)bc * HW);
    float4 p0 = xp[tid];
    float4 p1 = xp[tid + 256];
    float4 p2 = xp[tid + 512];
    float4 p3;
    if (tid < (HW4 - 768)) p3 = xp[768 + tid];
    else { p3.x = p3.y = p3.z = p3.w = -1e18f; }   // sentinel -> all profiles 0

    v2f acc2[NBINS];
    #pragma unroll
    for (int j = 0; j < NBINS; ++j) acc2[j] = (v2f){0.f, 0.f};

    // Uniform-spacing check (wave-uniform).
    const float D = e[1] - e[0];
    bool uniform = (D > 1e-6f);
    #pragma unroll
    for (int j = 1; j < NE - 1; ++j)
        uniform = uniform && (fabsf((e[j + 1] - e[j]) - D) <= 1e-4f * fabsf(D));

    const float sB = rfl(-20.0f * LOG2E);
    const float sC = rfl(20.0f * LOG2E * e[NE - 1]);

    if (uniform) {
        UniCoef u;
        const float sg  = -D * (1.0f / 3.0f) + 1e-6f;
        const float A   = rfl(-0.5f * LOG2E / (sg * sg));   // < 0 (log2 space)
        const float mu1 = e[0] + 0.5f * D;
        const float mu6 = e[0] + 5.5f * D;
        u.A  = A;
        u.B0 = rfl(-2.0f * A * e[0]); u.C0 = rfl(A * e[0] * e[0] + BIAS);
        u.B1 = rfl(-2.0f * A * mu1);  u.C1 = rfl(A * mu1 * mu1 + BIAS);
        u.B6 = rfl(-2.0f * A * mu6);  u.C6 = rfl(A * mu6 * mu6 + BIAS);
        u.dB = rfl(-2.0f * A * D);                    // > 0 (unbiased ratio)
        u.dC = rfl(A * D * (mu1 + mu1 + D));
        u.rho  = rfl(__builtin_amdgcn_exp2f(2.0f * A * D * D));   // < 1
        u.rho2 = rfl(u.rho * u.rho);
        u.HC = rfl((126.0f - u.dC) / u.dB);           // keep r finite
        u.sB = sB; u.sC = sC;

        // chunk 0 (waits only its own load)
        chain2((v2f){p0.x, p0.y}, u, acc2);
        chain2((v2f){p0.z, p0.w}, u, acc2);
        // chunk 1
        chain2((v2f){p1.x, p1.y}, u, acc2);
        chain2((v2f){p1.z, p1.w}, u, acc2);
        // chunk 2
        chain2((v2f){p2.x, p2.y}, u, acc2);
        chain2((v2f){p2.z, p2.w}, u, acc2);
        // chunk 3
        chain2((v2f){p3.x, p3.y}, u, acc2);
        chain2((v2f){p3.z, p3.w}, u, acc2);
    } else {
        // General path: direct per-bin quadratic exp2 (unbiased).
        float As[NE], Bs[NE], Cs[NE];
        {
            float mu = e[0];
            float s2 = (e[0] - e[1]) * (1.0f / 3.0f) + 1e-6f;
            float kk = -0.5f * LOG2E / (s2 * s2);
            As[0] = rfl(kk); Bs[0] = rfl(-2.0f * kk * mu); Cs[0] = rfl(kk * mu * mu);
        }
        #pragma unroll
        for (int j = 1; j < NE; ++j) {
            float mu = (e[j - 1] + e[j]) * 0.5f;
            float s2 = (e[j - 1] - e[j]) * (1.0f / 3.0f) + 1e-6f;
            float kk = -0.5f * LOG2E / (s2 * s2);
            As[j] = rfl(kk); Bs[j] = rfl(-2.0f * kk * mu); Cs[j] = rfl(kk * mu * mu);
        }
        float vsg[16] = {p0.x,p0.y,p0.z,p0.w, p1.x,p1.y,p1.z,p1.w,
                         p2.x,p2.y,p2.z,p2.w, p3.x,p3.y,p3.z,p3.w};
        #pragma unroll
        for (int k = 0; k < 16; ++k) {
            float v = vsg[k], v2 = v * v;
            #pragma unroll
            for (int j = 0; j < NE; ++j) {
                float arg = fmaf(As[j], v2, fmaf(Bs[j], v, Cs[j]));
                acc2[j].x += __builtin_amdgcn_exp2f(arg);
            }
            float den = 1.0f + __builtin_amdgcn_exp2f(fmaf(sB, v, sC));
            acc2[10].x += __builtin_amdgcn_rcpf(den);
        }
    }

    float acc[NBINS];
    #pragma unroll
    for (int j = 0; j < NBINS; ++j) acc[j] = acc2[j].x + acc2[j].y;

    // Wave (64-lane) reduce each accumulator.
    #pragma unroll
    for (int j = 0; j < NBINS; ++j) {
        float a = acc[j];
        #pragma unroll
        for (int off = 32; off > 0; off >>= 1)
            a += __shfl_down(a, off, 64);
        acc[j] = a;
    }

    // Cross-wave reduce via LDS (4 waves x 11 bins).
    __shared__ float red[4][NBINS];
    const int wave = tid >> 6;
    const int lane = tid & 63;
    if (lane == 0) {
        #pragma unroll
        for (int j = 0; j < NBINS; ++j) red[wave][j] = acc[j];
    }
    __syncthreads();
    if (tid < NBINS) {
        float s = red[0][tid] + red[1][tid] + red[2][tid] + red[3][tid];
        // Unbias Gaussian bins (uniform path only); sigmoid bin unbiased.
        const float unb = (uniform && tid < NE) ? 0x1p-88f : 1.0f;
        out[(size_t)bc * NBINS + tid] = s * unb;
    }
}

extern "C" void kernel_launch(void* const* d_in, const int* in_sizes, int n_in,
                              void* d_out, int out_size, void* d_ws, size_t ws_size,
                              hipStream_t stream) {
    const float* x     = (const float*)d_in[0];
    const float* edges = (const float*)d_in[1];
    float* out         = (float*)d_out;
    hist_kernel<<<dim3(16 * NCH), dim3(256), 0, stream>>>(x, edges, out);
}